// Round 1
// baseline (8576.727 us; speedup 1.0000x reference)
//
#include <hip/hip_runtime.h>
#include <cstdint>
#include <cstddef>

#define D 128
#define NNODES 100000

// ---------------------------------------------------------------------------
// deg[dst] += 1 for each edge
__global__ void deg_kernel(const int* __restrict__ dst, int E,
                           float* __restrict__ deg) {
    int i = blockIdx.x * blockDim.x + threadIdx.x;
    if (i < E) atomicAdd(&deg[dst[i]], 1.0f);
}

// deg -> 1/max(deg,1)  (in place)
__global__ void deginv_kernel(float* __restrict__ deg, int n) {
    int i = blockIdx.x * blockDim.x + threadIdx.x;
    if (i < n) deg[i] = 1.0f / fmaxf(deg[i], 1.0f);
}

// ---------------------------------------------------------------------------
// agg[dst] += h[src]   (32 lanes per edge, float4 per lane, dword atomics)
__global__ void scatter_kernel(const float* __restrict__ h,
                               const int* __restrict__ src,
                               const int* __restrict__ dst, int E,
                               float* __restrict__ agg) {
    long long tid = (long long)blockIdx.x * blockDim.x + threadIdx.x;
    int lane = (int)(tid & 31);
    long long e = tid >> 5;
    if (e >= E) return;
    int s = src[e];
    int d = dst[e];
    const float4 v = *(const float4*)(h + (long long)s * D + lane * 4);
    float* a = agg + (long long)d * D + lane * 4;
    atomicAdd(a + 0, v.x);
    atomicAdd(a + 1, v.y);
    atomicAdd(a + 2, v.z);
    atomicAdd(a + 3, v.w);
}

// ---------------------------------------------------------------------------
// h_out = act( (agg*deginv) @ Wn + h_in @ Ws + b [+ h_in] )
// Tile: 64 rows x 128 cols, BK=16, 256 threads, each thread 8x4 outputs.
template <bool RELU, bool RES>
__global__ __launch_bounds__(256) void gemm_fused(
    const float* __restrict__ agg,      // [N, D]
    const float* __restrict__ hin,      // [N, D]
    const float* __restrict__ deginv,   // [N]
    const float* __restrict__ wn,       // [D, D] row-major (k, n)
    const float* __restrict__ wsf,      // [D, D]
    const float* __restrict__ bias,     // [D]
    float* __restrict__ hout, int N) {
    __shared__ float As[64][16];    // row stride 64B -> float4-aligned rows
    __shared__ float Ws[16][128];

    const int t = threadIdx.x;
    const int row0 = blockIdx.x * 64;

    // output mapping: 8 row-groups x 32 col-groups
    const int rg = t >> 5;          // 0..7  -> rows rg*8 .. rg*8+7
    const int cg = t & 31;          // 0..31 -> cols cg*4 .. cg*4+3

    // A-load mapping: each thread loads one float4
    const int arow = t >> 2;        // 0..63
    const int acol = (t & 3) * 4;   // 0,4,8,12
    int lrow = row0 + arow;
    if (lrow >= N) lrow = N - 1;    // clamp (results discarded on write)

    // W-load mapping: each thread loads two float4 (8 floats of one row)
    const int wrow = t >> 4;        // 0..15
    const int wcol = (t & 15) * 8;  // 0..120

    float acc[8][4];
#pragma unroll
    for (int i = 0; i < 8; i++)
#pragma unroll
        for (int j = 0; j < 4; j++) acc[i][j] = 0.0f;

    for (int phase = 0; phase < 2; ++phase) {
        const float* A = phase ? hin : agg;
        const float* W = phase ? wsf : wn;
        const float scale = phase ? 1.0f : deginv[lrow];
        for (int kb = 0; kb < D; kb += 16) {
            __syncthreads();
            // stage A chunk [64][16]
            float4 av = *(const float4*)(A + (long long)lrow * D + kb + acol);
            As[arow][acol + 0] = av.x * scale;
            As[arow][acol + 1] = av.y * scale;
            As[arow][acol + 2] = av.z * scale;
            As[arow][acol + 3] = av.w * scale;
            // stage W chunk [16][128]
            float4 w0 = *(const float4*)(W + (long long)(kb + wrow) * D + wcol);
            float4 w1 = *(const float4*)(W + (long long)(kb + wrow) * D + wcol + 4);
            *(float4*)&Ws[wrow][wcol] = w0;
            *(float4*)&Ws[wrow][wcol + 4] = w1;
            __syncthreads();
#pragma unroll
            for (int k4 = 0; k4 < 16; k4 += 4) {
                float4 a4[8];
#pragma unroll
                for (int i = 0; i < 8; i++)
                    a4[i] = *(const float4*)&As[rg * 8 + i][k4];  // broadcast read
#pragma unroll
                for (int kk = 0; kk < 4; kk++) {
                    float4 wv = *(const float4*)&Ws[k4 + kk][cg * 4];  // conflict-free b128
#pragma unroll
                    for (int i = 0; i < 8; i++) {
                        const float av2 = ((const float*)&a4[i])[kk];
                        acc[i][0] = fmaf(av2, wv.x, acc[i][0]);
                        acc[i][1] = fmaf(av2, wv.y, acc[i][1]);
                        acc[i][2] = fmaf(av2, wv.z, acc[i][2]);
                        acc[i][3] = fmaf(av2, wv.w, acc[i][3]);
                    }
                }
            }
        }
    }

    // epilogue
    const int col = cg * 4;
    const float4 bv = *(const float4*)(bias + col);
#pragma unroll
    for (int i = 0; i < 8; i++) {
        int row = row0 + rg * 8 + i;
        if (row >= N) continue;
        float4 o;
        o.x = acc[i][0] + bv.x;
        o.y = acc[i][1] + bv.y;
        o.z = acc[i][2] + bv.z;
        o.w = acc[i][3] + bv.w;
        if (RES) {
            float4 r = *(const float4*)(hin + (long long)row * D + col);
            o.x += r.x; o.y += r.y; o.z += r.z; o.w += r.w;
        }
        if (RELU) {
            o.x = fmaxf(o.x, 0.0f);
            o.y = fmaxf(o.y, 0.0f);
            o.z = fmaxf(o.z, 0.0f);
            o.w = fmaxf(o.w, 0.0f);
        }
        *(float4*)(hout + (long long)row * D + col) = o;
    }
}

// ---------------------------------------------------------------------------
// logits[e] = dot(h[u], h[v])  (32 lanes per edge)
__global__ void decoder_kernel(const float* __restrict__ h,
                               const int* __restrict__ eli, int EL,
                               float* __restrict__ out) {
    long long tid = (long long)blockIdx.x * blockDim.x + threadIdx.x;
    int lane = (int)(tid & 31);
    long long e = tid >> 5;
    if (e >= EL) return;
    int u = eli[e];
    int v = eli[e + EL];
    float4 a = *(const float4*)(h + (long long)u * D + lane * 4);
    float4 b = *(const float4*)(h + (long long)v * D + lane * 4);
    float p = a.x * b.x + a.y * b.y + a.z * b.z + a.w * b.w;
#pragma unroll
    for (int off = 16; off; off >>= 1) p += __shfl_xor(p, off);
    if (lane == 0) out[e] = p;
}

// ---------------------------------------------------------------------------
static inline size_t align256(size_t x) { return (x + 255) & ~(size_t)255; }

extern "C" void kernel_launch(void* const* d_in, const int* in_sizes, int n_in,
                              void* d_out, int out_size, void* d_ws,
                              size_t ws_size, hipStream_t stream) {
    const float* x    = (const float*)d_in[0];   // [N, 128]
    const int*   ei   = (const int*)d_in[1];     // [2, E]
    const int*   eli  = (const int*)d_in[2];     // [2, EL]
    const float* wn   = (const float*)d_in[3];   // [3, 128, 128]
    const float* wsf  = (const float*)d_in[4];   // [3, 128, 128]
    const float* bias = (const float*)d_in[5];   // [3, 128]

    const int N  = in_sizes[0] / D;              // 100000
    const int E  = in_sizes[1] / 2;              // 1600000
    const int EL = in_sizes[2] / 2;              // 200000

    const int* src = ei;
    const int* dst = ei + E;

    // workspace layout
    char* p = (char*)d_ws;
    float* deg = (float*)p; p += align256((size_t)N * sizeof(float));
    float* agg = (float*)p; p += align256((size_t)N * D * sizeof(float));
    float* hA  = (float*)p; p += align256((size_t)N * D * sizeof(float));
    float* hB  = (float*)p;

    const size_t hbytes = (size_t)N * D * sizeof(float);
    const int scatter_blocks = (int)(((long long)E * 32 + 255) / 256);
    const int gemm_blocks = (N + 63) / 64;

    // degree (identical across layers; ws is re-poisoned every call -> re-zero)
    hipMemsetAsync(deg, 0, (size_t)N * sizeof(float), stream);
    deg_kernel<<<(E + 255) / 256, 256, 0, stream>>>(dst, E, deg);
    deginv_kernel<<<(N + 255) / 256, 256, 0, stream>>>(deg, N);

    // ---- layer 0: relu(conv(x)) -> hA
    hipMemsetAsync(agg, 0, hbytes, stream);
    scatter_kernel<<<scatter_blocks, 256, 0, stream>>>(x, src, dst, E, agg);
    gemm_fused<true, false><<<gemm_blocks, 256, 0, stream>>>(
        agg, x, deg, wn + 0 * D * D, wsf + 0 * D * D, bias + 0 * D, hA, N);

    // ---- layer 1: relu(conv(hA) + hA) -> hB
    hipMemsetAsync(agg, 0, hbytes, stream);
    scatter_kernel<<<scatter_blocks, 256, 0, stream>>>(hA, src, dst, E, agg);
    gemm_fused<true, true><<<gemm_blocks, 256, 0, stream>>>(
        agg, hA, deg, wn + 1 * D * D, wsf + 1 * D * D, bias + 1 * D, hB, N);

    // ---- layer 2: conv(hB) + hB -> hA
    hipMemsetAsync(agg, 0, hbytes, stream);
    scatter_kernel<<<scatter_blocks, 256, 0, stream>>>(hB, src, dst, E, agg);
    gemm_fused<false, true><<<gemm_blocks, 256, 0, stream>>>(
        agg, hB, deg, wn + 2 * D * D, wsf + 2 * D * D, bias + 2 * D, hA, N);

    // ---- decoder
    decoder_kernel<<<(int)(((long long)EL * 32 + 255) / 256), 256, 0, stream>>>(
        hA, eli, EL, (float*)d_out);
}

// Round 3
// 913.468 us; speedup vs baseline: 9.3892x; 9.3892x over previous
//
#include <hip/hip_runtime.h>
#include <cstdint>
#include <cstddef>

#define D 128

// ---------------------------------------------------------------------------
// histogram: counts[dst]++ (int atomics)
__global__ void hist_kernel(const int* __restrict__ dst, int E,
                            int* __restrict__ counts) {
    int i = blockIdx.x * blockDim.x + threadIdx.x;
    if (i < E) atomicAdd(&counts[dst[i]], 1);
}

// per-block sums of counts (for deterministic scan)
__global__ void block_sum_kernel(const int* __restrict__ counts, int n,
                                 int* __restrict__ bsum) {
    __shared__ int sh[256];
    int t = threadIdx.x;
    int i = blockIdx.x * 256 + t;
    sh[t] = (i < n) ? counts[i] : 0;
    __syncthreads();
    for (int off = 128; off; off >>= 1) {
        if (t < off) sh[t] += sh[t + off];
        __syncthreads();
    }
    if (t == 0) bsum[blockIdx.x] = sh[0];
}

// serial exclusive scan of block sums (nb ~ 391, trivial)
__global__ void scan_bsum_kernel(int* __restrict__ bsum, int nb,
                                 int* __restrict__ row_ptr, int N, int E) {
    if (blockIdx.x == 0 && threadIdx.x == 0) {
        int run = 0;
        for (int k = 0; k < nb; k++) { int v = bsum[k]; bsum[k] = run; run += v; }
        row_ptr[N] = E;
    }
}

// per-block exclusive scan + block offset -> row_ptr
__global__ void block_scan_kernel(const int* __restrict__ counts, int n,
                                  const int* __restrict__ bsum,
                                  int* __restrict__ row_ptr) {
    __shared__ int sh[256];
    int t = threadIdx.x;
    int i = blockIdx.x * 256 + t;
    int v = (i < n) ? counts[i] : 0;
    sh[t] = v;
    __syncthreads();
    for (int off = 1; off < 256; off <<= 1) {
        int add = (t >= off) ? sh[t - off] : 0;
        __syncthreads();
        sh[t] += add;
        __syncthreads();
    }
    if (i < n) row_ptr[i] = bsum[blockIdx.x] + sh[t] - v;
}

// place each edge's src into its dst bucket
__global__ void fill_kernel(const int* __restrict__ src,
                            const int* __restrict__ dst, int E,
                            const int* __restrict__ row_ptr,
                            int* __restrict__ cursor,
                            int* __restrict__ csr_src) {
    int i = blockIdx.x * blockDim.x + threadIdx.x;
    if (i < E) {
        int d = dst[i];
        int pos = row_ptr[d] + atomicAdd(&cursor[d], 1);
        csr_src[pos] = src[i];
    }
}

// ---------------------------------------------------------------------------
// agg[node] = (1/deg) * sum_{e in CSR[node]} h[csr_src[e]]
// one 64-lane wave per node, float2 per lane (512B/row), unroll 4
__global__ __launch_bounds__(256) void gather_agg(
    const float* __restrict__ h, const int* __restrict__ row_ptr,
    const int* __restrict__ csr_src,
    float* __restrict__ agg, int N) {
    int node = (int)((blockIdx.x * (size_t)blockDim.x + threadIdx.x) >> 6);
    int lane = threadIdx.x & 63;
    if (node >= N) return;
    int beg = row_ptr[node], end = row_ptr[node + 1];
    const int col = lane * 2;
    float2 a0 = {0.f, 0.f}, a1 = {0.f, 0.f}, a2 = {0.f, 0.f}, a3 = {0.f, 0.f};
    int e = beg;
    for (; e + 4 <= end; e += 4) {
        int s0 = csr_src[e + 0];
        int s1 = csr_src[e + 1];
        int s2 = csr_src[e + 2];
        int s3 = csr_src[e + 3];
        float2 v0 = *(const float2*)(h + (size_t)s0 * D + col);
        float2 v1 = *(const float2*)(h + (size_t)s1 * D + col);
        float2 v2 = *(const float2*)(h + (size_t)s2 * D + col);
        float2 v3 = *(const float2*)(h + (size_t)s3 * D + col);
        a0.x += v0.x; a0.y += v0.y;
        a1.x += v1.x; a1.y += v1.y;
        a2.x += v2.x; a2.y += v2.y;
        a3.x += v3.x; a3.y += v3.y;
    }
    for (; e < end; ++e) {
        int s = csr_src[e];
        float2 v = *(const float2*)(h + (size_t)s * D + col);
        a0.x += v.x; a0.y += v.y;
    }
    // degree == CSR segment length by construction
    float sc = 1.0f / fmaxf((float)(end - beg), 1.0f);
    float2 o;
    o.x = (a0.x + a1.x + a2.x + a3.x) * sc;
    o.y = (a0.y + a1.y + a2.y + a3.y) * sc;
    *(float2*)(agg + (size_t)node * D + col) = o;
}

// ---------------------------------------------------------------------------
// h_out = act( agg @ Wn + h_in @ Ws + b [+ h_in] )   (agg pre-scaled by 1/deg)
// Tile: 64 rows x 128 cols, BK=16, 256 threads, each thread 8x4 outputs.
template <bool RELU, bool RES>
__global__ __launch_bounds__(256) void gemm_fused(
    const float* __restrict__ agg,      // [N, D]
    const float* __restrict__ hin,      // [N, D]
    const float* __restrict__ wn,       // [D, D] row-major (k, n)
    const float* __restrict__ wsf,      // [D, D]
    const float* __restrict__ bias,     // [D]
    float* __restrict__ hout, int N) {
    __shared__ float As[64][16];
    __shared__ float Ws[16][128];

    const int t = threadIdx.x;
    const int row0 = blockIdx.x * 64;

    const int rg = t >> 5;          // 0..7  -> rows rg*8 .. rg*8+7
    const int cg = t & 31;          // 0..31 -> cols cg*4 .. cg*4+3

    const int arow = t >> 2;        // 0..63
    const int acol = (t & 3) * 4;   // 0,4,8,12
    int lrow = row0 + arow;
    if (lrow >= N) lrow = N - 1;    // clamp (results discarded on write)

    const int wrow = t >> 4;        // 0..15
    const int wcol = (t & 15) * 8;  // 0..120

    float acc[8][4];
#pragma unroll
    for (int i = 0; i < 8; i++)
#pragma unroll
        for (int j = 0; j < 4; j++) acc[i][j] = 0.0f;

    for (int phase = 0; phase < 2; ++phase) {
        const float* A = phase ? hin : agg;
        const float* W = phase ? wsf : wn;
        for (int kb = 0; kb < D; kb += 16) {
            __syncthreads();
            float4 av = *(const float4*)(A + (long long)lrow * D + kb + acol);
            *(float4*)&As[arow][acol] = av;
            float4 w0 = *(const float4*)(W + (long long)(kb + wrow) * D + wcol);
            float4 w1 = *(const float4*)(W + (long long)(kb + wrow) * D + wcol + 4);
            *(float4*)&Ws[wrow][wcol] = w0;
            *(float4*)&Ws[wrow][wcol + 4] = w1;
            __syncthreads();
#pragma unroll
            for (int k4 = 0; k4 < 16; k4 += 4) {
                float4 a4[8];
#pragma unroll
                for (int i = 0; i < 8; i++)
                    a4[i] = *(const float4*)&As[rg * 8 + i][k4];
#pragma unroll
                for (int kk = 0; kk < 4; kk++) {
                    float4 wv = *(const float4*)&Ws[k4 + kk][cg * 4];
#pragma unroll
                    for (int i = 0; i < 8; i++) {
                        const float av2 = ((const float*)&a4[i])[kk];
                        acc[i][0] = fmaf(av2, wv.x, acc[i][0]);
                        acc[i][1] = fmaf(av2, wv.y, acc[i][1]);
                        acc[i][2] = fmaf(av2, wv.z, acc[i][2]);
                        acc[i][3] = fmaf(av2, wv.w, acc[i][3]);
                    }
                }
            }
        }
    }

    const int col = cg * 4;
    const float4 bv = *(const float4*)(bias + col);
#pragma unroll
    for (int i = 0; i < 8; i++) {
        int row = row0 + rg * 8 + i;
        if (row >= N) continue;
        float4 o;
        o.x = acc[i][0] + bv.x;
        o.y = acc[i][1] + bv.y;
        o.z = acc[i][2] + bv.z;
        o.w = acc[i][3] + bv.w;
        if (RES) {
            float4 r = *(const float4*)(hin + (long long)row * D + col);
            o.x += r.x; o.y += r.y; o.z += r.z; o.w += r.w;
        }
        if (RELU) {
            o.x = fmaxf(o.x, 0.0f);
            o.y = fmaxf(o.y, 0.0f);
            o.z = fmaxf(o.z, 0.0f);
            o.w = fmaxf(o.w, 0.0f);
        }
        *(float4*)(hout + (long long)row * D + col) = o;
    }
}

// ---------------------------------------------------------------------------
// logits[e] = dot(h[u], h[v])  (32 lanes per edge)
__global__ void decoder_kernel(const float* __restrict__ h,
                               const int* __restrict__ eli, int EL,
                               float* __restrict__ out) {
    long long tid = (long long)blockIdx.x * blockDim.x + threadIdx.x;
    int lane = (int)(tid & 31);
    long long e = tid >> 5;
    if (e >= EL) return;
    int u = eli[e];
    int v = eli[e + EL];
    float4 a = *(const float4*)(h + (long long)u * D + lane * 4);
    float4 b = *(const float4*)(h + (long long)v * D + lane * 4);
    float p = a.x * b.x + a.y * b.y + a.z * b.z + a.w * b.w;
#pragma unroll
    for (int off = 16; off; off >>= 1) p += __shfl_xor(p, off);
    if (lane == 0) out[e] = p;
}

// ---------------------------------------------------------------------------
static inline size_t align256(size_t x) { return (x + 255) & ~(size_t)255; }

extern "C" void kernel_launch(void* const* d_in, const int* in_sizes, int n_in,
                              void* d_out, int out_size, void* d_ws,
                              size_t ws_size, hipStream_t stream) {
    const float* x    = (const float*)d_in[0];   // [N, 128]
    const int*   ei   = (const int*)d_in[1];     // [2, E]
    const int*   eli  = (const int*)d_in[2];     // [2, EL]
    const float* wn   = (const float*)d_in[3];   // [3, 128, 128]
    const float* wsf  = (const float*)d_in[4];   // [3, 128, 128]
    const float* bias = (const float*)d_in[5];   // [3, 128]

    const int N  = in_sizes[0] / D;              // 100000
    const int E  = in_sizes[1] / 2;              // 1600000
    const int EL = in_sizes[2] / 2;              // 200000

    const int* src = ei;
    const int* dst = ei + E;

    // workspace layout
    char* p = (char*)d_ws;
    int*   counts  = (int*)p;   p += align256((size_t)N * sizeof(int));  // reused as cursor
    int*   row_ptr = (int*)p;   p += align256((size_t)(N + 1) * sizeof(int));
    int*   bsum    = (int*)p;   p += align256((size_t)1024 * sizeof(int));
    int*   csr_src = (int*)p;   p += align256((size_t)E * sizeof(int));
    float* agg     = (float*)p; p += align256((size_t)N * D * sizeof(float));
    float* hA      = (float*)p; p += align256((size_t)N * D * sizeof(float));
    float* hB      = (float*)p;

    const int nb = (N + 255) / 256;              // scan blocks (391)
    const int eb = (E + 255) / 256;              // edge blocks
    const int gemm_blocks = (N + 63) / 64;
    const int gather_blocks = (N + 3) / 4;       // 4 nodes (waves) per 256-block

    // ---- CSR build (once; reused by all 3 layers)
    hipMemsetAsync(counts, 0, (size_t)N * sizeof(int), stream);
    hist_kernel<<<eb, 256, 0, stream>>>(dst, E, counts);
    block_sum_kernel<<<nb, 256, 0, stream>>>(counts, N, bsum);
    scan_bsum_kernel<<<1, 1, 0, stream>>>(bsum, nb, row_ptr, N, E);
    block_scan_kernel<<<nb, 256, 0, stream>>>(counts, N, bsum, row_ptr);
    hipMemsetAsync(counts, 0, (size_t)N * sizeof(int), stream);  // now cursor
    fill_kernel<<<eb, 256, 0, stream>>>(src, dst, E, row_ptr, counts, csr_src);

    // ---- layer 0: relu(conv(x)) -> hA
    gather_agg<<<gather_blocks, 256, 0, stream>>>(x, row_ptr, csr_src, agg, N);
    gemm_fused<true, false><<<gemm_blocks, 256, 0, stream>>>(
        agg, x, wn + 0 * D * D, wsf + 0 * D * D, bias + 0 * D, hA, N);

    // ---- layer 1: relu(conv(hA) + hA) -> hB
    gather_agg<<<gather_blocks, 256, 0, stream>>>(hA, row_ptr, csr_src, agg, N);
    gemm_fused<true, true><<<gemm_blocks, 256, 0, stream>>>(
        agg, hA, wn + 1 * D * D, wsf + 1 * D * D, bias + 1 * D, hB, N);

    // ---- layer 2: conv(hB) + hB -> hA
    gather_agg<<<gather_blocks, 256, 0, stream>>>(hB, row_ptr, csr_src, agg, N);
    gemm_fused<false, true><<<gemm_blocks, 256, 0, stream>>>(
        agg, hB, wn + 2 * D * D, wsf + 2 * D * D, bias + 2 * D, hA, N);

    // ---- decoder
    decoder_kernel<<<(int)(((long long)EL * 32 + 255) / 256), 256, 0, stream>>>(
        hA, eli, EL, (float*)d_out);
}